// Round 5
// baseline (1103.162 us; speedup 1.0000x reference)
//
#include <hip/hip_runtime.h>
#include <hip/hip_bf16.h>
#include <math.h>

#define N 8192
#define D 256
#define EPSF 1e-6f
#define NCHUNK 64  // N / 128 column tiles

typedef __attribute__((ext_vector_type(8))) short short8v;
typedef __attribute__((ext_vector_type(4))) float f32x4;

__device__ __forceinline__ unsigned short f2bf(float x) {
    __hip_bfloat16 h = __float2bfloat16(x);
    return *(unsigned short*)&h;
}
__device__ __forceinline__ float bf2f(unsigned short u) {
    __hip_bfloat16 h = *(__hip_bfloat16*)&u;
    return __bfloat162float(h);
}
__device__ __forceinline__ float4 ntload4(const float* p) {
    f32x4 r = __builtin_nontemporal_load((const f32x4*)p);
    return make_float4(r.x, r.y, r.z, r.w);
}
__device__ __forceinline__ void ntstore4(float* p, float4 v) {
    f32x4 r = {v.x, v.y, v.z, v.w};
    __builtin_nontemporal_store(r, (f32x4*)p);
}

// ---------------- split z -> Bh, Bl (bf16 hi/lo) ----------------
__global__ __launch_bounds__(256) void split_kernel(const float* __restrict__ x,
                                                    unsigned short* __restrict__ hi,
                                                    unsigned short* __restrict__ lo) {
    int i = (blockIdx.x * 256 + threadIdx.x) * 4;
    float4 v = *(const float4*)&x[i];
    ushort4 h, l;
    float a;
    a = v.x; h.x = f2bf(a); l.x = f2bf(a - bf2f(h.x));
    a = v.y; h.y = f2bf(a); l.y = f2bf(a - bf2f(h.y));
    a = v.z; h.z = f2bf(a); l.z = f2bf(a - bf2f(h.z));
    a = v.w; h.w = f2bf(a); l.w = f2bf(a - bf2f(h.w));
    *(ushort4*)&hi[i] = h;
    *(ushort4*)&lo[i] = l;
}

// ---------------- zW = z @ W, split to Ah, Al ----------------
__global__ __launch_bounds__(256) void zw_kernel(const float* __restrict__ z,
                                                 const float* __restrict__ W,
                                                 unsigned short* __restrict__ Ah,
                                                 unsigned short* __restrict__ Al) {
    __shared__ float zs[32 * D];
    int rowBase = blockIdx.x * 32;
    const float4* zg = (const float4*)(z + (size_t)rowBase * D);
    float4* zs4 = (float4*)zs;
    for (int i = threadIdx.x; i < 32 * D / 4; i += 256) zs4[i] = zg[i];
    __syncthreads();

    float acc[32];
#pragma unroll
    for (int r = 0; r < 32; ++r) acc[r] = 0.f;
    int col = threadIdx.x;
    for (int kb = 0; kb < D; kb += 4) {
        float w0 = W[(size_t)(kb + 0) * D + col];
        float w1 = W[(size_t)(kb + 1) * D + col];
        float w2 = W[(size_t)(kb + 2) * D + col];
        float w3 = W[(size_t)(kb + 3) * D + col];
#pragma unroll
        for (int r = 0; r < 32; ++r) {
            float4 zv = *(const float4*)&zs[r * D + kb];
            acc[r] = fmaf(zv.x, w0, acc[r]);
            acc[r] = fmaf(zv.y, w1, acc[r]);
            acc[r] = fmaf(zv.z, w2, acc[r]);
            acc[r] = fmaf(zv.w, w3, acc[r]);
        }
    }
#pragma unroll
    for (int r = 0; r < 32; ++r) {
        float a = acc[r];
        unsigned short h = f2bf(a);
        unsigned short l = f2bf(a - bf2f(h));
        Ah[(size_t)(rowBase + r) * D + col] = h;
        Al[(size_t)(rowBase + r) * D + col] = l;
    }
}

// ---------------- shared MFMA K-loop (verified r2/r3: 0 staging conflicts) ----------------
__device__ __forceinline__ void mfma_kloop(
    const unsigned short* __restrict__ Ah, const unsigned short* __restrict__ Al,
    const unsigned short* __restrict__ Bh, const unsigned short* __restrict__ Bl,
    int rowBase, int colBase, int t, unsigned short (*lds)[128][32], f32x4 (&acc)[4][4]) {
    int lane = t & 63;
    int w = t >> 6;
    int wr = (w >> 1), wc = w & 1;
    int fr = lane & 15;
    int fg = lane >> 4;

    const int srow = t >> 1;
    const int s0 = (t & 1) * 2;
    const int swrow = (srow >> 1) & 3;

    const unsigned short* g0 = Ah + (size_t)(rowBase + srow) * D;
    const unsigned short* g1 = Al + (size_t)(rowBase + srow) * D;
    const unsigned short* g2 = Bh + (size_t)(colBase + srow) * D;
    const unsigned short* g3 = Bl + (size_t)(colBase + srow) * D;

    float4 pre[8];
    auto loadstep = [&](int kt) {
        pre[0] = *(const float4*)(g0 + kt + s0 * 8);
        pre[1] = *(const float4*)(g0 + kt + s0 * 8 + 8);
        pre[2] = *(const float4*)(g1 + kt + s0 * 8);
        pre[3] = *(const float4*)(g1 + kt + s0 * 8 + 8);
        pre[4] = *(const float4*)(g2 + kt + s0 * 8);
        pre[5] = *(const float4*)(g2 + kt + s0 * 8 + 8);
        pre[6] = *(const float4*)(g3 + kt + s0 * 8);
        pre[7] = *(const float4*)(g3 + kt + s0 * 8 + 8);
    };
    auto writestep = [&]() {
#pragma unroll
        for (int tile = 0; tile < 4; ++tile) {
            *(float4*)&lds[tile][srow][((s0 + 0) ^ swrow) * 8] = pre[tile * 2 + 0];
            *(float4*)&lds[tile][srow][((s0 + 1) ^ swrow) * 8] = pre[tile * 2 + 1];
        }
    };

    loadstep(0);
    for (int kt = 0; kt < D; kt += 32) {
        __syncthreads();
        writestep();
        __syncthreads();
        if (kt + 32 < D) loadstep(kt + 32);

        short8v bhf[4], blf[4];
#pragma unroll
        for (int n = 0; n < 4; ++n) {
            int row = wc * 64 + n * 16 + fr;
            int sl = fg ^ ((row >> 1) & 3);
            bhf[n] = *(const short8v*)&lds[2][row][sl * 8];
            blf[n] = *(const short8v*)&lds[3][row][sl * 8];
        }
#pragma unroll
        for (int m = 0; m < 4; ++m) {
            int row = wr * 64 + m * 16 + fr;
            int sl = fg ^ ((row >> 1) & 3);
            short8v ahf = *(const short8v*)&lds[0][row][sl * 8];
            short8v alf = *(const short8v*)&lds[1][row][sl * 8];
#pragma unroll
            for (int n = 0; n < 4; ++n) {
                acc[m][n] = __builtin_amdgcn_mfma_f32_16x16x32_bf16(ahf, bhf[n], acc[m][n], 0, 0, 0);
                acc[m][n] = __builtin_amdgcn_mfma_f32_16x16x32_bf16(ahf, blf[n], acc[m][n], 0, 0, 0);
                acc[m][n] = __builtin_amdgcn_mfma_f32_16x16x32_bf16(alf, bhf[n], acc[m][n], 0, 0, 0);
            }
        }
    }
}

// XCD-banded tile mapping (col-major within each XCD's 8-row band)
__device__ __forceinline__ void tile_map(int bid, int& rowBase, int& colBase, int& bx) {
    int xcd = bid & 7;
    int idx = bid >> 3;
    bx = idx >> 3;
    int by = xcd * 8 + (idx & 7);
    rowBase = by * 128;
    colBase = bx * 128;
}

// ---------------- Pass 1: per-row partials P1=Σs, P2=Σs·q, P3=Σq (no out write, no atomics) ----------------
__global__ __launch_bounds__(256, 4) void sim_pass1_kernel(
    const unsigned short* __restrict__ Ah, const unsigned short* __restrict__ Al,
    const unsigned short* __restrict__ Bh, const unsigned short* __restrict__ Bl,
    const float* __restrict__ beta, const float* __restrict__ Q,
    float* __restrict__ p1, float* __restrict__ p2, float* __restrict__ p3) {
    __shared__ unsigned short lds[4][128][32];

    int rowBase, colBase, bx;
    tile_map(blockIdx.x, rowBase, colBase, bx);

    int t = threadIdx.x;
    int lane = t & 63;
    int w = t >> 6;
    int wr = w >> 1, wc = w & 1;
    int fr = lane & 15;
    int fg = lane >> 4;

    f32x4 acc[4][4];
#pragma unroll
    for (int m = 0; m < 4; ++m)
#pragma unroll
        for (int n = 0; n < 4; ++n) acc[m][n] = (f32x4){0.f, 0.f, 0.f, 0.f};

    mfma_kloop(Ah, Al, Bh, Bl, rowBase, colBase, t, lds, acc);

    __syncthreads();  // all waves done with staging LDS
    float* scratch = (float*)lds + w * (16 * 68);                       // 4 x 4352 B
    float(*buf)[128][4] = (float(*)[128][4])((char*)lds + 17408);       // 2 x 128 x 4 f32

#pragma unroll
    for (int m = 0; m < 4; ++m) {
#pragma unroll
        for (int n = 0; n < 4; ++n)
#pragma unroll
            for (int reg = 0; reg < 4; ++reg)
                scratch[(fg * 4 + reg) * 68 + n * 16 + fr] = acc[m][n][reg];

#pragma unroll
        for (int sub = 0; sub < 4; ++sub) {
            int rloc = sub * 4 + fg;
            int row_local = wr * 64 + m * 16 + rloc;
            int i = rowBase + row_local;
            int col = colBase + wc * 64 + fr * 4;
            float4 sv = *(const float4*)&scratch[rloc * 68 + fr * 4];
            float bi = beta[i];
            float4 s;
            s.x = sqrtf(fmaxf(sv.x - bi, 0.f) + EPSF);
            s.y = sqrtf(fmaxf(sv.y - bi, 0.f) + EPSF);
            s.z = sqrtf(fmaxf(sv.z - bi, 0.f) + EPSF);
            s.w = sqrtf(fmaxf(sv.w - bi, 0.f) + EPSF);
            float4 qv = ntload4(Q + (size_t)i * N + col);
            float ps = s.x + s.y + s.z + s.w;
            float pq = s.x * qv.x + s.y * qv.y + s.z * qv.z + s.w * qv.w;
            float qs = qv.x + qv.y + qv.z + qv.w;
#pragma unroll
            for (int msk = 1; msk <= 8; msk <<= 1) {
                ps += __shfl_xor(ps, msk, 64);
                pq += __shfl_xor(pq, msk, 64);
                qs += __shfl_xor(qs, msk, 64);
            }
            if (fr == 0) {
                buf[wc][row_local][0] = ps;
                buf[wc][row_local][1] = pq;
                buf[wc][row_local][2] = qs;
            }
        }
    }
    __syncthreads();
    if (t < 128) {
        size_t pidx = (size_t)bx * N + rowBase + t;
        p1[pidx] = buf[0][t][0] + buf[1][t][0];
        p2[pidx] = buf[0][t][1] + buf[1][t][1];
        p3[pidx] = buf[0][t][2] + buf[1][t][2];
    }
}

// ---------------- Reduce: Sq, wsum -> shalf = 0.5/Sq, winv = 1/wsum ----------------
__global__ __launch_bounds__(256) void reduce_kernel(const float* __restrict__ p1,
                                                     const float* __restrict__ p2,
                                                     const float* __restrict__ p3,
                                                     float* __restrict__ shalf,
                                                     float* __restrict__ winv) {
    int i = blockIdx.x * 256 + threadIdx.x;
    float s1 = 0.f, s2 = 0.f, s3 = 0.f;
    for (int c = 0; c < NCHUNK; ++c) {
        size_t idx = (size_t)c * N + i;
        s1 += p1[idx];
        s2 += p2[idx];
        s3 += p3[idx];
    }
    float shi = 0.5f / s3;
    shalf[i] = shi;
    winv[i] = 1.0f / (0.5f * s1 + shi * s2);
}

// ---------------- Pass 2: recompute sim, write normalized out (nt stores, no atomics) ----------------
__global__ __launch_bounds__(256, 4) void sim_pass2_kernel(
    const unsigned short* __restrict__ Ah, const unsigned short* __restrict__ Al,
    const unsigned short* __restrict__ Bh, const unsigned short* __restrict__ Bl,
    const float* __restrict__ beta, const float* __restrict__ Q,
    const float* __restrict__ shalf, const float* __restrict__ winv,
    float* __restrict__ out) {
    __shared__ unsigned short lds[4][128][32];

    int rowBase, colBase, bx;
    tile_map(blockIdx.x, rowBase, colBase, bx);

    int t = threadIdx.x;
    int lane = t & 63;
    int w = t >> 6;
    int wr = w >> 1, wc = w & 1;
    int fr = lane & 15;
    int fg = lane >> 4;

    f32x4 acc[4][4];
#pragma unroll
    for (int m = 0; m < 4; ++m)
#pragma unroll
        for (int n = 0; n < 4; ++n) acc[m][n] = (f32x4){0.f, 0.f, 0.f, 0.f};

    mfma_kloop(Ah, Al, Bh, Bl, rowBase, colBase, t, lds, acc);

    __syncthreads();
    float* scratch = (float*)lds + w * (16 * 68);

#pragma unroll
    for (int m = 0; m < 4; ++m) {
#pragma unroll
        for (int n = 0; n < 4; ++n)
#pragma unroll
            for (int reg = 0; reg < 4; ++reg)
                scratch[(fg * 4 + reg) * 68 + n * 16 + fr] = acc[m][n][reg];

#pragma unroll
        for (int sub = 0; sub < 4; ++sub) {
            int rloc = sub * 4 + fg;
            int i = rowBase + wr * 64 + m * 16 + rloc;
            int col = colBase + wc * 64 + fr * 4;
            float4 sv = *(const float4*)&scratch[rloc * 68 + fr * 4];
            float bi = beta[i];
            float shi = shalf[i];
            float wv = winv[i];
            float4 qv = ntload4(Q + (size_t)i * N + col);
            float4 o;
            o.x = sqrtf(fmaxf(sv.x - bi, 0.f) + EPSF) * fmaf(qv.x, shi, 0.5f) * wv;
            o.y = sqrtf(fmaxf(sv.y - bi, 0.f) + EPSF) * fmaf(qv.y, shi, 0.5f) * wv;
            o.z = sqrtf(fmaxf(sv.z - bi, 0.f) + EPSF) * fmaf(qv.z, shi, 0.5f) * wv;
            o.w = sqrtf(fmaxf(sv.w - bi, 0.f) + EPSF) * fmaf(qv.w, shi, 0.5f) * wv;
            ntstore4(out + (size_t)i * N + col, o);
        }
    }
}

extern "C" void kernel_launch(void* const* d_in, const int* in_sizes, int n_in,
                              void* d_out, int out_size, void* d_ws, size_t ws_size,
                              hipStream_t stream) {
    const float* z = (const float*)d_in[0];
    const float* W = (const float*)d_in[1];
    const float* beta = (const float*)d_in[2];
    const float* Q = (const float*)d_in[3];
    float* out = (float*)d_out;

    unsigned short* Ah = (unsigned short*)d_ws;   // N*D bf16 each (4 MB x 4)
    unsigned short* Al = Ah + (size_t)N * D;
    unsigned short* Bh = Al + (size_t)N * D;
    unsigned short* Bl = Bh + (size_t)N * D;
    float* p1 = (float*)(Bl + (size_t)N * D);     // NCHUNK*N f32 each (2 MB x 3)
    float* p2 = p1 + (size_t)NCHUNK * N;
    float* p3 = p2 + (size_t)NCHUNK * N;
    float* shalf = p3 + (size_t)NCHUNK * N;       // N f32
    float* winv = shalf + N;                      // N f32

    split_kernel<<<(N * D / 4) / 256, 256, 0, stream>>>(z, Bh, Bl);
    zw_kernel<<<N / 32, 256, 0, stream>>>(z, W, Ah, Al);
    sim_pass1_kernel<<<4096, 256, 0, stream>>>(Ah, Al, Bh, Bl, beta, Q, p1, p2, p3);
    reduce_kernel<<<N / 256, 256, 0, stream>>>(p1, p2, p3, shalf, winv);
    sim_pass2_kernel<<<4096, 256, 0, stream>>>(Ah, Al, Bh, Bl, beta, Q, shalf, winv, out);
}

// Round 6
// 743.086 us; speedup vs baseline: 1.4846x; 1.4846x over previous
//
#include <hip/hip_runtime.h>
#include <hip/hip_bf16.h>
#include <math.h>

#define N 8192
#define D 256
#define EPSF 1e-6f

typedef __attribute__((ext_vector_type(8))) short short8v;
typedef __attribute__((ext_vector_type(4))) float f32x4;

__device__ __forceinline__ unsigned short f2bf(float x) {
    __hip_bfloat16 h = __float2bfloat16(x);
    return *(unsigned short*)&h;
}
__device__ __forceinline__ float bf2f(unsigned short u) {
    __hip_bfloat16 h = *(__hip_bfloat16*)&u;
    return __bfloat162float(h);
}

// ---------------- split z -> Bh, Bl (bf16 hi/lo) ----------------
__global__ __launch_bounds__(256) void split_kernel(const float* __restrict__ x,
                                                    unsigned short* __restrict__ hi,
                                                    unsigned short* __restrict__ lo) {
    int i = (blockIdx.x * 256 + threadIdx.x) * 4;
    float4 v = *(const float4*)&x[i];
    ushort4 h, l;
    float a;
    a = v.x; h.x = f2bf(a); l.x = f2bf(a - bf2f(h.x));
    a = v.y; h.y = f2bf(a); l.y = f2bf(a - bf2f(h.y));
    a = v.z; h.z = f2bf(a); l.z = f2bf(a - bf2f(h.z));
    a = v.w; h.w = f2bf(a); l.w = f2bf(a - bf2f(h.w));
    *(ushort4*)&hi[i] = h;
    *(ushort4*)&lo[i] = l;
}

// ---------------- zW = z @ W, split to Ah, Al ----------------
__global__ __launch_bounds__(256) void zw_kernel(const float* __restrict__ z,
                                                 const float* __restrict__ W,
                                                 unsigned short* __restrict__ Ah,
                                                 unsigned short* __restrict__ Al) {
    __shared__ float zs[32 * D];
    int rowBase = blockIdx.x * 32;
    const float4* zg = (const float4*)(z + (size_t)rowBase * D);
    float4* zs4 = (float4*)zs;
    for (int i = threadIdx.x; i < 32 * D / 4; i += 256) zs4[i] = zg[i];
    __syncthreads();

    float acc[32];
#pragma unroll
    for (int r = 0; r < 32; ++r) acc[r] = 0.f;
    int col = threadIdx.x;
    for (int kb = 0; kb < D; kb += 4) {
        float w0 = W[(size_t)(kb + 0) * D + col];
        float w1 = W[(size_t)(kb + 1) * D + col];
        float w2 = W[(size_t)(kb + 2) * D + col];
        float w3 = W[(size_t)(kb + 3) * D + col];
#pragma unroll
        for (int r = 0; r < 32; ++r) {
            float4 zv = *(const float4*)&zs[r * D + kb];
            acc[r] = fmaf(zv.x, w0, acc[r]);
            acc[r] = fmaf(zv.y, w1, acc[r]);
            acc[r] = fmaf(zv.z, w2, acc[r]);
            acc[r] = fmaf(zv.w, w3, acc[r]);
        }
    }
#pragma unroll
    for (int r = 0; r < 32; ++r) {
        float a = acc[r];
        unsigned short h = f2bf(a);
        unsigned short l = f2bf(a - bf2f(h));
        Ah[(size_t)(rowBase + r) * D + col] = h;
        Al[(size_t)(rowBase + r) * D + col] = l;
    }
}

// ---------------- shared MFMA K-loop (verified r2-r5: 0 staging conflicts) ----------------
__device__ __forceinline__ void mfma_kloop(
    const unsigned short* __restrict__ Ah, const unsigned short* __restrict__ Al,
    const unsigned short* __restrict__ Bh, const unsigned short* __restrict__ Bl,
    int rowBase, int colBase, int t, unsigned short (*lds)[128][32], f32x4 (&acc)[4][4]) {
    int lane = t & 63;
    int w = t >> 6;
    int wr = (w >> 1), wc = w & 1;
    int fr = lane & 15;
    int fg = lane >> 4;

    const int srow = t >> 1;
    const int s0 = (t & 1) * 2;
    const int swrow = (srow >> 1) & 3;

    const unsigned short* g0 = Ah + (size_t)(rowBase + srow) * D;
    const unsigned short* g1 = Al + (size_t)(rowBase + srow) * D;
    const unsigned short* g2 = Bh + (size_t)(colBase + srow) * D;
    const unsigned short* g3 = Bl + (size_t)(colBase + srow) * D;

    float4 pre[8];
    auto loadstep = [&](int kt) {
        pre[0] = *(const float4*)(g0 + kt + s0 * 8);
        pre[1] = *(const float4*)(g0 + kt + s0 * 8 + 8);
        pre[2] = *(const float4*)(g1 + kt + s0 * 8);
        pre[3] = *(const float4*)(g1 + kt + s0 * 8 + 8);
        pre[4] = *(const float4*)(g2 + kt + s0 * 8);
        pre[5] = *(const float4*)(g2 + kt + s0 * 8 + 8);
        pre[6] = *(const float4*)(g3 + kt + s0 * 8);
        pre[7] = *(const float4*)(g3 + kt + s0 * 8 + 8);
    };
    auto writestep = [&]() {
#pragma unroll
        for (int tile = 0; tile < 4; ++tile) {
            *(float4*)&lds[tile][srow][((s0 + 0) ^ swrow) * 8] = pre[tile * 2 + 0];
            *(float4*)&lds[tile][srow][((s0 + 1) ^ swrow) * 8] = pre[tile * 2 + 1];
        }
    };

    loadstep(0);
    for (int kt = 0; kt < D; kt += 32) {
        __syncthreads();
        writestep();
        __syncthreads();
        if (kt + 32 < D) loadstep(kt + 32);

        short8v bhf[4], blf[4];
#pragma unroll
        for (int n = 0; n < 4; ++n) {
            int row = wc * 64 + n * 16 + fr;
            int sl = fg ^ ((row >> 1) & 3);
            bhf[n] = *(const short8v*)&lds[2][row][sl * 8];
            blf[n] = *(const short8v*)&lds[3][row][sl * 8];
        }
#pragma unroll
        for (int m = 0; m < 4; ++m) {
            int row = wr * 64 + m * 16 + fr;
            int sl = fg ^ ((row >> 1) & 3);
            short8v ahf = *(const short8v*)&lds[0][row][sl * 8];
            short8v alf = *(const short8v*)&lds[1][row][sl * 8];
#pragma unroll
            for (int n = 0; n < 4; ++n) {
                acc[m][n] = __builtin_amdgcn_mfma_f32_16x16x32_bf16(ahf, bhf[n], acc[m][n], 0, 0, 0);
                acc[m][n] = __builtin_amdgcn_mfma_f32_16x16x32_bf16(ahf, blf[n], acc[m][n], 0, 0, 0);
                acc[m][n] = __builtin_amdgcn_mfma_f32_16x16x32_bf16(alf, bhf[n], acc[m][n], 0, 0, 0);
            }
        }
    }
}

// XCD-banded tile mapping (col-major within each XCD's 8-row band)
__device__ __forceinline__ void tile_map(int bid, int& rowBase, int& colBase) {
    int xcd = bid & 7;
    int idx = bid >> 3;
    int bx = idx >> 3;
    int by = xcd * 8 + (idx & 7);
    rowBase = by * 128;
    colBase = bx * 128;
}

// ---------------- Pass A: s = sqrt(relu(sim-beta)+eps) -> d_out (f32), no Q ----------------
__global__ __launch_bounds__(256, 4) void gemm_s_kernel(
    const unsigned short* __restrict__ Ah, const unsigned short* __restrict__ Al,
    const unsigned short* __restrict__ Bh, const unsigned short* __restrict__ Bl,
    const float* __restrict__ beta, float* __restrict__ sbuf) {
    __shared__ unsigned short lds[4][128][32];

    int rowBase, colBase;
    tile_map(blockIdx.x, rowBase, colBase);

    int t = threadIdx.x;
    int lane = t & 63;
    int w = t >> 6;
    int wr = w >> 1, wc = w & 1;
    int fr = lane & 15;
    int fg = lane >> 4;

    f32x4 acc[4][4];
#pragma unroll
    for (int m = 0; m < 4; ++m)
#pragma unroll
        for (int n = 0; n < 4; ++n) acc[m][n] = (f32x4){0.f, 0.f, 0.f, 0.f};

    mfma_kloop(Ah, Al, Bh, Bl, rowBase, colBase, t, lds, acc);

    // direct epilogue: D layout col = fr, row = fg*4 + reg
#pragma unroll
    for (int m = 0; m < 4; ++m) {
#pragma unroll
        for (int reg = 0; reg < 4; ++reg) {
            int i = rowBase + wr * 64 + m * 16 + fg * 4 + reg;
            float bi = beta[i];
            float* srow = sbuf + (size_t)i * N + colBase + wc * 64 + fr;
#pragma unroll
            for (int n = 0; n < 4; ++n) {
                srow[n * 16] = sqrtf(fmaxf(acc[m][n][reg] - bi, 0.f) + EPSF);
            }
        }
    }
}

// ---------------- Pass B1: per-row stats over (s, Q): shalf = 0.5/Σq, winv = 1/wsum ----------------
__global__ __launch_bounds__(256) void rowstats_kernel(const float* __restrict__ sbuf,
                                                       const float* __restrict__ Q,
                                                       float* __restrict__ shalf,
                                                       float* __restrict__ winv) {
    int row = blockIdx.x;
    const float4* s4 = (const float4*)(sbuf + (size_t)row * N);
    const float4* q4 = (const float4*)(Q + (size_t)row * N);
    float ps = 0.f, pq = 0.f, qs = 0.f;
    for (int k = threadIdx.x; k < N / 4; k += 256) {
        float4 s = s4[k];
        float4 q = q4[k];
        ps += s.x + s.y + s.z + s.w;
        pq += s.x * q.x + s.y * q.y + s.z * q.z + s.w * q.w;
        qs += q.x + q.y + q.z + q.w;
    }
#pragma unroll
    for (int off = 1; off < 64; off <<= 1) {
        ps += __shfl_xor(ps, off, 64);
        pq += __shfl_xor(pq, off, 64);
        qs += __shfl_xor(qs, off, 64);
    }
    __shared__ float red[12];
    int wv = threadIdx.x >> 6;
    if ((threadIdx.x & 63) == 0) {
        red[wv * 3 + 0] = ps;
        red[wv * 3 + 1] = pq;
        red[wv * 3 + 2] = qs;
    }
    __syncthreads();
    if (threadIdx.x == 0) {
        ps = red[0] + red[3] + red[6] + red[9];
        pq = red[1] + red[4] + red[7] + red[10];
        qs = red[2] + red[5] + red[8] + red[11];
        float sh = 0.5f / qs;
        shalf[row] = sh;
        winv[row] = 1.0f / (0.5f * ps + sh * pq);
    }
}

// ---------------- Pass B2: in-place finalize out = s * (q*shalf + 0.5) * winv ----------------
__global__ __launch_bounds__(256) void finalize_kernel(float* __restrict__ out,
                                                       const float* __restrict__ Q,
                                                       const float* __restrict__ shalf,
                                                       const float* __restrict__ winv) {
    int row = blockIdx.x;
    float sh = shalf[row];
    float wv = winv[row];
    float4* o4 = (float4*)(out + (size_t)row * N);
    const float4* q4 = (const float4*)(Q + (size_t)row * N);
    for (int k = threadIdx.x; k < N / 4; k += 256) {
        float4 s = o4[k];
        float4 q = q4[k];
        float4 o;
        o.x = s.x * fmaf(q.x, sh, 0.5f) * wv;
        o.y = s.y * fmaf(q.y, sh, 0.5f) * wv;
        o.z = s.z * fmaf(q.z, sh, 0.5f) * wv;
        o.w = s.w * fmaf(q.w, sh, 0.5f) * wv;
        o4[k] = o;
    }
}

extern "C" void kernel_launch(void* const* d_in, const int* in_sizes, int n_in,
                              void* d_out, int out_size, void* d_ws, size_t ws_size,
                              hipStream_t stream) {
    const float* z = (const float*)d_in[0];
    const float* W = (const float*)d_in[1];
    const float* beta = (const float*)d_in[2];
    const float* Q = (const float*)d_in[3];
    float* out = (float*)d_out;

    unsigned short* Ah = (unsigned short*)d_ws;  // N*D bf16 each (4 MB x 4)
    unsigned short* Al = Ah + (size_t)N * D;
    unsigned short* Bh = Al + (size_t)N * D;
    unsigned short* Bl = Bh + (size_t)N * D;
    float* shalf = (float*)(Bl + (size_t)N * D);  // N f32
    float* winv = shalf + N;                      // N f32

    split_kernel<<<(N * D / 4) / 256, 256, 0, stream>>>(z, Bh, Bl);
    zw_kernel<<<N / 32, 256, 0, stream>>>(z, W, Ah, Al);
    gemm_s_kernel<<<4096, 256, 0, stream>>>(Ah, Al, Bh, Bl, beta, out);
    rowstats_kernel<<<N, 256, 0, stream>>>(out, Q, shalf, winv);
    finalize_kernel<<<N, 256, 0, stream>>>(out, Q, shalf, winv);
}

// Round 7
// 325.085 us; speedup vs baseline: 3.3935x; 2.2858x over previous
//
#include <hip/hip_runtime.h>
#include <hip/hip_bf16.h>
#include <math.h>

#define N 8192
#define D 256
#define EPSF 1e-6f

typedef __attribute__((ext_vector_type(8))) short short8v;
typedef __attribute__((ext_vector_type(4))) float f32x4;

__device__ __forceinline__ unsigned short f2bf(float x) {
    __hip_bfloat16 h = __float2bfloat16(x);
    return *(unsigned short*)&h;
}
__device__ __forceinline__ float bf2f(unsigned short u) {
    __hip_bfloat16 h = *(__hip_bfloat16*)&u;
    return __bfloat162float(h);
}
__device__ __forceinline__ f32x4 ntload4(const float* p) {
    return __builtin_nontemporal_load((const f32x4*)p);
}
__device__ __forceinline__ void ntstore4(float* p, f32x4 v) {
    __builtin_nontemporal_store(v, (f32x4*)p);
}

// async global->LDS, 16B per lane; LDS dest = wave-uniform base + lane*16
#define GLOAD_LDS16(gp, lp)                                                                  \
    __builtin_amdgcn_global_load_lds((const __attribute__((address_space(1))) unsigned int*)(gp), \
                                     (__attribute__((address_space(3))) unsigned int*)(lp), 16, 0, 0)

// ---------------- split z -> Bh, Bl (bf16 hi/lo) ----------------
__global__ __launch_bounds__(256) void split_kernel(const float* __restrict__ x,
                                                    unsigned short* __restrict__ hi,
                                                    unsigned short* __restrict__ lo) {
    int i = (blockIdx.x * 256 + threadIdx.x) * 4;
    float4 v = *(const float4*)&x[i];
    ushort4 h, l;
    float a;
    a = v.x; h.x = f2bf(a); l.x = f2bf(a - bf2f(h.x));
    a = v.y; h.y = f2bf(a); l.y = f2bf(a - bf2f(h.y));
    a = v.z; h.z = f2bf(a); l.z = f2bf(a - bf2f(h.z));
    a = v.w; h.w = f2bf(a); l.w = f2bf(a - bf2f(h.w));
    *(ushort4*)&hi[i] = h;
    *(ushort4*)&lo[i] = l;
}

// ---------------- zW = z @ W, split to Ah, Al ----------------
__global__ __launch_bounds__(256) void zw_kernel(const float* __restrict__ z,
                                                 const float* __restrict__ W,
                                                 unsigned short* __restrict__ Ah,
                                                 unsigned short* __restrict__ Al) {
    __shared__ float zs[32 * D];
    int rowBase = blockIdx.x * 32;
    const float4* zg = (const float4*)(z + (size_t)rowBase * D);
    float4* zs4 = (float4*)zs;
    for (int i = threadIdx.x; i < 32 * D / 4; i += 256) zs4[i] = zg[i];
    __syncthreads();

    float acc[32];
#pragma unroll
    for (int r = 0; r < 32; ++r) acc[r] = 0.f;
    int col = threadIdx.x;
    for (int kb = 0; kb < D; kb += 4) {
        float w0 = W[(size_t)(kb + 0) * D + col];
        float w1 = W[(size_t)(kb + 1) * D + col];
        float w2 = W[(size_t)(kb + 2) * D + col];
        float w3 = W[(size_t)(kb + 3) * D + col];
#pragma unroll
        for (int r = 0; r < 32; ++r) {
            float4 zv = *(const float4*)&zs[r * D + kb];
            acc[r] = fmaf(zv.x, w0, acc[r]);
            acc[r] = fmaf(zv.y, w1, acc[r]);
            acc[r] = fmaf(zv.z, w2, acc[r]);
            acc[r] = fmaf(zv.w, w3, acc[r]);
        }
    }
#pragma unroll
    for (int r = 0; r < 32; ++r) {
        float a = acc[r];
        unsigned short h = f2bf(a);
        unsigned short l = f2bf(a - bf2f(h));
        Ah[(size_t)(rowBase + r) * D + col] = h;
        Al[(size_t)(rowBase + r) * D + col] = l;
    }
}

// XCD-banded tile mapping (col-major within each XCD's 8-row band)
__device__ __forceinline__ void tile_map(int bid, int& rowBase, int& colBase) {
    int xcd = bid & 7;
    int idx = bid >> 3;
    int bx = idx >> 3;
    int by = xcd * 8 + (idx & 7);
    rowBase = by * 128;
    colBase = bx * 128;
}

// ---------------- Pass A: s = sqrt(relu(sim-beta)+eps) -> d_out (f32), no Q ----------------
// 128x128 tile, 4 waves, BK=32. Staging: global_load_lds dwordx4 with pre-swizzled
// per-lane SOURCE address so the linear LDS dest lands in the XOR slot layout the MFMA
// frag reads expect (lds slot sl of row r holds global slot sl ^ ((r>>1)&3)).
__global__ __launch_bounds__(256, 4) void gemm_s_kernel(
    const unsigned short* __restrict__ Ah, const unsigned short* __restrict__ Al,
    const unsigned short* __restrict__ Bh, const unsigned short* __restrict__ Bl,
    const float* __restrict__ beta, float* __restrict__ sbuf) {
    __shared__ unsigned short lds[4][128][32];  // 32 KB, reused as epilogue scratch

    int rowBase, colBase;
    tile_map(blockIdx.x, rowBase, colBase);

    int t = threadIdx.x;
    int lane = t & 63;
    int w = t >> 6;
    int wr = w >> 1, wc = w & 1;
    int fr = lane & 15;
    int fg = lane >> 4;

    // wave w stages tile w: 0=Ah 1=Al 2=Bh 3=Bl
    const unsigned short* tsrc = (w == 0) ? Ah : (w == 1) ? Al : (w == 2) ? Bh : Bl;
    int tRB = (w < 2) ? rowBase : colBase;
    int slot_src = (lane & 3) ^ ((lane >> 3) & 3);  // swz(r) for r=j*16+(lane>>2) is j-invariant
    const unsigned short* gt = tsrc + (size_t)(tRB + (lane >> 2)) * D + slot_src * 8;

    f32x4 acc[4][4];
#pragma unroll
    for (int m = 0; m < 4; ++m)
#pragma unroll
        for (int n = 0; n < 4; ++n) acc[m][n] = (f32x4){0.f, 0.f, 0.f, 0.f};

    for (int kt = 0; kt < D; kt += 32) {
        __syncthreads();  // prev iter's frag reads done (compiler drains lgkm before barrier)
#pragma unroll
        for (int j = 0; j < 8; ++j) {
            GLOAD_LDS16(gt + kt + j * 16 * D, &lds[w][j * 16][0]);
        }
        __syncthreads();  // compiler drains vmcnt(0) before barrier -> tile complete

        short8v bhf[4], blf[4];
#pragma unroll
        for (int n = 0; n < 4; ++n) {
            int row = wc * 64 + n * 16 + fr;
            int sl = fg ^ ((row >> 1) & 3);
            bhf[n] = *(const short8v*)&lds[2][row][sl * 8];
            blf[n] = *(const short8v*)&lds[3][row][sl * 8];
        }
#pragma unroll
        for (int m = 0; m < 4; ++m) {
            int row = wr * 64 + m * 16 + fr;
            int sl = fg ^ ((row >> 1) & 3);
            short8v ahf = *(const short8v*)&lds[0][row][sl * 8];
            short8v alf = *(const short8v*)&lds[1][row][sl * 8];
#pragma unroll
            for (int n = 0; n < 4; ++n) {
                acc[m][n] = __builtin_amdgcn_mfma_f32_16x16x32_bf16(ahf, bhf[n], acc[m][n], 0, 0, 0);
                acc[m][n] = __builtin_amdgcn_mfma_f32_16x16x32_bf16(ahf, blf[n], acc[m][n], 0, 0, 0);
                acc[m][n] = __builtin_amdgcn_mfma_f32_16x16x32_bf16(alf, bhf[n], acc[m][n], 0, 0, 0);
            }
        }
    }

    // epilogue: repack through per-wave LDS scratch -> 256B-run nontemporal float4 stores
    __syncthreads();
    float* scratch = (float*)lds + w * (16 * 68);

#pragma unroll
    for (int m = 0; m < 4; ++m) {
#pragma unroll
        for (int n = 0; n < 4; ++n)
#pragma unroll
            for (int reg = 0; reg < 4; ++reg)
                scratch[(fg * 4 + reg) * 68 + n * 16 + fr] = acc[m][n][reg];

#pragma unroll
        for (int sub = 0; sub < 4; ++sub) {
            int rloc = sub * 4 + fg;
            int i = rowBase + wr * 64 + m * 16 + rloc;
            int col = colBase + wc * 64 + fr * 4;
            float4 sv = *(const float4*)&scratch[rloc * 68 + fr * 4];
            float bi = beta[i];
            f32x4 o;
            o.x = sqrtf(fmaxf(sv.x - bi, 0.f) + EPSF);
            o.y = sqrtf(fmaxf(sv.y - bi, 0.f) + EPSF);
            o.z = sqrtf(fmaxf(sv.z - bi, 0.f) + EPSF);
            o.w = sqrtf(fmaxf(sv.w - bi, 0.f) + EPSF);
            ntstore4(sbuf + (size_t)i * N + col, o);
        }
        __syncthreads();
    }
}

// ---------------- Pass B: fused row stats + in-place finalize ----------------
// One block per row. Stage s-row and Q-row in LDS (nt loads), reduce 3 stats,
// finalize out = s*(q*shalf+0.5)*winv with nt stores. 804 MB total HBM.
__global__ __launch_bounds__(512) void rownorm_kernel(float* __restrict__ out,
                                                      const float* __restrict__ Q) {
    __shared__ f32x4 sb[N / 4];  // 32 KB
    __shared__ f32x4 qb[N / 4];  // 32 KB
    __shared__ float red[24];

    int row = blockIdx.x;
    int t = threadIdx.x;
    const float* srow = out + (size_t)row * N;
    const float* qrow = Q + (size_t)row * N;

    float ps = 0.f, pq = 0.f, qs = 0.f;
    for (int k = t; k < N / 4; k += 512) {
        f32x4 s = ntload4(srow + k * 4);
        f32x4 q = ntload4(qrow + k * 4);
        sb[k] = s;
        qb[k] = q;
        ps += s.x + s.y + s.z + s.w;
        pq += s.x * q.x + s.y * q.y + s.z * q.z + s.w * q.w;
        qs += q.x + q.y + q.z + q.w;
    }
#pragma unroll
    for (int off = 1; off < 64; off <<= 1) {
        ps += __shfl_xor(ps, off, 64);
        pq += __shfl_xor(pq, off, 64);
        qs += __shfl_xor(qs, off, 64);
    }
    if ((t & 63) == 0) {
        int wv = t >> 6;
        red[wv * 3 + 0] = ps;
        red[wv * 3 + 1] = pq;
        red[wv * 3 + 2] = qs;
    }
    __syncthreads();
    float tps = 0.f, tpq = 0.f, tqs = 0.f;
#pragma unroll
    for (int i = 0; i < 8; ++i) {
        tps += red[i * 3 + 0];
        tpq += red[i * 3 + 1];
        tqs += red[i * 3 + 2];
    }
    float sh = 0.5f / tqs;
    float wv = 1.0f / (0.5f * tps + sh * tpq);

    float* orow = out + (size_t)row * N;
    for (int k = t; k < N / 4; k += 512) {
        f32x4 s = sb[k];
        f32x4 q = qb[k];
        f32x4 o;
        o.x = s.x * fmaf(q.x, sh, 0.5f) * wv;
        o.y = s.y * fmaf(q.y, sh, 0.5f) * wv;
        o.z = s.z * fmaf(q.z, sh, 0.5f) * wv;
        o.w = s.w * fmaf(q.w, sh, 0.5f) * wv;
        ntstore4(orow + k * 4, o);
    }
}

extern "C" void kernel_launch(void* const* d_in, const int* in_sizes, int n_in,
                              void* d_out, int out_size, void* d_ws, size_t ws_size,
                              hipStream_t stream) {
    const float* z = (const float*)d_in[0];
    const float* W = (const float*)d_in[1];
    const float* beta = (const float*)d_in[2];
    const float* Q = (const float*)d_in[3];
    float* out = (float*)d_out;

    unsigned short* Ah = (unsigned short*)d_ws;  // N*D bf16 each (4 MB x 4)
    unsigned short* Al = Ah + (size_t)N * D;
    unsigned short* Bh = Al + (size_t)N * D;
    unsigned short* Bl = Bh + (size_t)N * D;

    split_kernel<<<(N * D / 4) / 256, 256, 0, stream>>>(z, Bh, Bl);
    zw_kernel<<<N / 32, 256, 0, stream>>>(z, W, Ah, Al);
    gemm_s_kernel<<<4096, 256, 0, stream>>>(Ah, Al, Bh, Bl, beta, out);
    rownorm_kernel<<<N, 512, 0, stream>>>(out, Q);
}

// Round 8
// 303.730 us; speedup vs baseline: 3.6321x; 1.0703x over previous
//
#include <hip/hip_runtime.h>
#include <hip/hip_bf16.h>
#include <math.h>

#define N 8192
#define D 256
#define EPSF 1e-6f

typedef __attribute__((ext_vector_type(8))) short short8v;
typedef __attribute__((ext_vector_type(4))) float f32x4;
typedef __attribute__((ext_vector_type(4))) unsigned short u16x4;

__device__ __forceinline__ unsigned short f2bf(float x) {
    __hip_bfloat16 h = __float2bfloat16(x);
    return *(unsigned short*)&h;
}
__device__ __forceinline__ float bf2f(unsigned short u) {
    __hip_bfloat16 h = *(__hip_bfloat16*)&u;
    return __bfloat162float(h);
}
__device__ __forceinline__ float bfu2f(unsigned short u) {
    unsigned int x = ((unsigned int)u) << 16;
    float f;
    __builtin_memcpy(&f, &x, 4);
    return f;
}
__device__ __forceinline__ f32x4 ntload4(const float* p) {
    return __builtin_nontemporal_load((const f32x4*)p);
}
__device__ __forceinline__ void ntstore4(float* p, f32x4 v) {
    __builtin_nontemporal_store(v, (f32x4*)p);
}

// async global->LDS, 16B per lane; LDS dest = wave-uniform base + lane*16
#define GLOAD_LDS16(gp, lp)                                                                  \
    __builtin_amdgcn_global_load_lds((const __attribute__((address_space(1))) unsigned int*)(gp), \
                                     (__attribute__((address_space(3))) unsigned int*)(lp), 16, 0, 0)

// ---------------- split z -> Bh, Bl (bf16 hi/lo) ----------------
__global__ __launch_bounds__(256) void split_kernel(const float* __restrict__ x,
                                                    unsigned short* __restrict__ hi,
                                                    unsigned short* __restrict__ lo) {
    int i = (blockIdx.x * 256 + threadIdx.x) * 4;
    float4 v = *(const float4*)&x[i];
    ushort4 h, l;
    float a;
    a = v.x; h.x = f2bf(a); l.x = f2bf(a - bf2f(h.x));
    a = v.y; h.y = f2bf(a); l.y = f2bf(a - bf2f(h.y));
    a = v.z; h.z = f2bf(a); l.z = f2bf(a - bf2f(h.z));
    a = v.w; h.w = f2bf(a); l.w = f2bf(a - bf2f(h.w));
    *(ushort4*)&hi[i] = h;
    *(ushort4*)&lo[i] = l;
}

// ---------------- zW = z @ W, split to Ah, Al ----------------
__global__ __launch_bounds__(256) void zw_kernel(const float* __restrict__ z,
                                                 const float* __restrict__ W,
                                                 unsigned short* __restrict__ Ah,
                                                 unsigned short* __restrict__ Al) {
    __shared__ float zs[32 * D];
    int rowBase = blockIdx.x * 32;
    const float4* zg = (const float4*)(z + (size_t)rowBase * D);
    float4* zs4 = (float4*)zs;
    for (int i = threadIdx.x; i < 32 * D / 4; i += 256) zs4[i] = zg[i];
    __syncthreads();

    float acc[32];
#pragma unroll
    for (int r = 0; r < 32; ++r) acc[r] = 0.f;
    int col = threadIdx.x;
    for (int kb = 0; kb < D; kb += 4) {
        float w0 = W[(size_t)(kb + 0) * D + col];
        float w1 = W[(size_t)(kb + 1) * D + col];
        float w2 = W[(size_t)(kb + 2) * D + col];
        float w3 = W[(size_t)(kb + 3) * D + col];
#pragma unroll
        for (int r = 0; r < 32; ++r) {
            float4 zv = *(const float4*)&zs[r * D + kb];
            acc[r] = fmaf(zv.x, w0, acc[r]);
            acc[r] = fmaf(zv.y, w1, acc[r]);
            acc[r] = fmaf(zv.z, w2, acc[r]);
            acc[r] = fmaf(zv.w, w3, acc[r]);
        }
    }
#pragma unroll
    for (int r = 0; r < 32; ++r) {
        float a = acc[r];
        unsigned short h = f2bf(a);
        unsigned short l = f2bf(a - bf2f(h));
        Ah[(size_t)(rowBase + r) * D + col] = h;
        Al[(size_t)(rowBase + r) * D + col] = l;
    }
}

// XCD-banded tile mapping (col-major within each XCD's 8-row band)
__device__ __forceinline__ void tile_map(int bid, int& rowBase, int& colBase) {
    int xcd = bid & 7;
    int idx = bid >> 3;
    int bx = idx >> 3;
    int by = xcd * 8 + (idx & 7);
    rowBase = by * 128;
    colBase = bx * 128;
}

// ---------------- Pass A: s = sqrt(relu(sim-beta)+eps), stored bf16 (ws) or f32 (d_out) ----------------
template <bool BF16S>
__global__ __launch_bounds__(256, 4) void gemm_s_kernel(
    const unsigned short* __restrict__ Ah, const unsigned short* __restrict__ Al,
    const unsigned short* __restrict__ Bh, const unsigned short* __restrict__ Bl,
    const float* __restrict__ beta, unsigned short* __restrict__ sbf,
    float* __restrict__ sf32) {
    __shared__ unsigned short lds[4][128][32];  // 32 KB, reused as epilogue scratch

    int rowBase, colBase;
    tile_map(blockIdx.x, rowBase, colBase);

    int t = threadIdx.x;
    int lane = t & 63;
    int w = t >> 6;
    int wr = w >> 1, wc = w & 1;
    int fr = lane & 15;
    int fg = lane >> 4;

    // wave w stages tile w: 0=Ah 1=Al 2=Bh 3=Bl
    const unsigned short* tsrc = (w == 0) ? Ah : (w == 1) ? Al : (w == 2) ? Bh : Bl;
    int tRB = (w < 2) ? rowBase : colBase;
    int slot_src = (lane & 3) ^ ((lane >> 3) & 3);  // swz(r) for r=j*16+(lane>>2) is j-invariant
    const unsigned short* gt = tsrc + (size_t)(tRB + (lane >> 2)) * D + slot_src * 8;

    f32x4 acc[4][4];
#pragma unroll
    for (int m = 0; m < 4; ++m)
#pragma unroll
        for (int n = 0; n < 4; ++n) acc[m][n] = (f32x4){0.f, 0.f, 0.f, 0.f};

    for (int kt = 0; kt < D; kt += 32) {
        __syncthreads();  // prev iter's frag reads done
#pragma unroll
        for (int j = 0; j < 8; ++j) {
            GLOAD_LDS16(gt + kt + j * 16 * D, &lds[w][j * 16][0]);
        }
        __syncthreads();  // vmcnt(0) drained before barrier -> tile complete

        short8v bhf[4], blf[4];
#pragma unroll
        for (int n = 0; n < 4; ++n) {
            int row = wc * 64 + n * 16 + fr;
            int sl = fg ^ ((row >> 1) & 3);
            bhf[n] = *(const short8v*)&lds[2][row][sl * 8];
            blf[n] = *(const short8v*)&lds[3][row][sl * 8];
        }
#pragma unroll
        for (int m = 0; m < 4; ++m) {
            int row = wr * 64 + m * 16 + fr;
            int sl = fg ^ ((row >> 1) & 3);
            short8v ahf = *(const short8v*)&lds[0][row][sl * 8];
            short8v alf = *(const short8v*)&lds[1][row][sl * 8];
#pragma unroll
            for (int n = 0; n < 4; ++n) {
                acc[m][n] = __builtin_amdgcn_mfma_f32_16x16x32_bf16(ahf, bhf[n], acc[m][n], 0, 0, 0);
                acc[m][n] = __builtin_amdgcn_mfma_f32_16x16x32_bf16(ahf, blf[n], acc[m][n], 0, 0, 0);
                acc[m][n] = __builtin_amdgcn_mfma_f32_16x16x32_bf16(alf, bhf[n], acc[m][n], 0, 0, 0);
            }
        }
    }

    // epilogue: repack through per-wave LDS scratch -> coalesced nontemporal stores
    __syncthreads();
    float* scratch = (float*)lds + w * (16 * 68);

#pragma unroll
    for (int m = 0; m < 4; ++m) {
#pragma unroll
        for (int n = 0; n < 4; ++n)
#pragma unroll
            for (int reg = 0; reg < 4; ++reg)
                scratch[(fg * 4 + reg) * 68 + n * 16 + fr] = acc[m][n][reg];

#pragma unroll
        for (int sub = 0; sub < 4; ++sub) {
            int rloc = sub * 4 + fg;
            int i = rowBase + wr * 64 + m * 16 + rloc;
            int col = colBase + wc * 64 + fr * 4;
            float4 sv = *(const float4*)&scratch[rloc * 68 + fr * 4];
            float bi = beta[i];
            float s0 = sqrtf(fmaxf(sv.x - bi, 0.f) + EPSF);
            float s1 = sqrtf(fmaxf(sv.y - bi, 0.f) + EPSF);
            float s2 = sqrtf(fmaxf(sv.z - bi, 0.f) + EPSF);
            float s3 = sqrtf(fmaxf(sv.w - bi, 0.f) + EPSF);
            if constexpr (BF16S) {
                u16x4 o = {f2bf(s0), f2bf(s1), f2bf(s2), f2bf(s3)};
                __builtin_nontemporal_store(o, (u16x4*)(sbf + (size_t)i * N + col));
            } else {
                f32x4 o = {s0, s1, s2, s3};
                ntstore4(sf32 + (size_t)i * N + col, o);
            }
        }
        __syncthreads();
    }
}

// ---------------- Pass B: fused row stats + finalize ----------------
// One block/row. Stats from full-precision loads; s and Q staged in LDS as bf16 (32 KB).
template <bool BF16S>
__global__ __launch_bounds__(512) void rownorm_kernel(float* __restrict__ out,
                                                      const float* __restrict__ Q,
                                                      const unsigned short* __restrict__ sbf) {
    __shared__ short8v sb[N / 8];  // 16 KB
    __shared__ short8v qb[N / 8];  // 16 KB
    __shared__ float red[24];

    int row = blockIdx.x;
    int t = threadIdx.x;
    const float* qrow = Q + (size_t)row * N;

    float ps = 0.f, pq = 0.f, qs = 0.f;
    for (int k = t; k < N / 8; k += 512) {
        float s[8];
        short8v spack;
        if constexpr (BF16S) {
            spack = __builtin_nontemporal_load((const short8v*)(sbf + (size_t)row * N + k * 8));
#pragma unroll
            for (int j = 0; j < 8; ++j) s[j] = bfu2f((unsigned short)spack[j]);
        } else {
            f32x4 a = ntload4(out + (size_t)row * N + k * 8);
            f32x4 b = ntload4(out + (size_t)row * N + k * 8 + 4);
            s[0] = a.x; s[1] = a.y; s[2] = a.z; s[3] = a.w;
            s[4] = b.x; s[5] = b.y; s[6] = b.z; s[7] = b.w;
#pragma unroll
            for (int j = 0; j < 8; ++j) spack[j] = (short)f2bf(s[j]);
        }
        sb[k] = spack;
        f32x4 q0 = ntload4(qrow + k * 8);
        f32x4 q1 = ntload4(qrow + k * 8 + 4);
        float q[8] = {q0.x, q0.y, q0.z, q0.w, q1.x, q1.y, q1.z, q1.w};
        short8v qpack;
#pragma unroll
        for (int j = 0; j < 8; ++j) qpack[j] = (short)f2bf(q[j]);
        qb[k] = qpack;
#pragma unroll
        for (int j = 0; j < 8; ++j) {
            ps += s[j];
            pq += s[j] * q[j];
            qs += q[j];
        }
    }
#pragma unroll
    for (int off = 1; off < 64; off <<= 1) {
        ps += __shfl_xor(ps, off, 64);
        pq += __shfl_xor(pq, off, 64);
        qs += __shfl_xor(qs, off, 64);
    }
    if ((t & 63) == 0) {
        int wv = t >> 6;
        red[wv * 3 + 0] = ps;
        red[wv * 3 + 1] = pq;
        red[wv * 3 + 2] = qs;
    }
    __syncthreads();
    float tps = 0.f, tpq = 0.f, tqs = 0.f;
#pragma unroll
    for (int i = 0; i < 8; ++i) {
        tps += red[i * 3 + 0];
        tpq += red[i * 3 + 1];
        tqs += red[i * 3 + 2];
    }
    float sh = 0.5f / tqs;
    float wv = 1.0f / (0.5f * tps + sh * tpq);

    float* orow = out + (size_t)row * N;
    for (int k = t; k < N / 8; k += 512) {
        short8v sp = sb[k];
        short8v qp = qb[k];
        f32x4 o0, o1;
#pragma unroll
        for (int j = 0; j < 4; ++j)
            o0[j] = bfu2f((unsigned short)sp[j]) * fmaf(bfu2f((unsigned short)qp[j]), sh, 0.5f) * wv;
#pragma unroll
        for (int j = 0; j < 4; ++j)
            o1[j] = bfu2f((unsigned short)sp[j + 4]) * fmaf(bfu2f((unsigned short)qp[j + 4]), sh, 0.5f) * wv;
        ntstore4(orow + k * 8, o0);
        ntstore4(orow + k * 8 + 4, o1);
    }
}

extern "C" void kernel_launch(void* const* d_in, const int* in_sizes, int n_in,
                              void* d_out, int out_size, void* d_ws, size_t ws_size,
                              hipStream_t stream) {
    const float* z = (const float*)d_in[0];
    const float* W = (const float*)d_in[1];
    const float* beta = (const float*)d_in[2];
    const float* Q = (const float*)d_in[3];
    float* out = (float*)d_out;

    unsigned short* Ah = (unsigned short*)d_ws;  // N*D bf16 each (4 MB x 4)
    unsigned short* Al = Ah + (size_t)N * D;
    unsigned short* Bh = Al + (size_t)N * D;
    unsigned short* Bl = Bh + (size_t)N * D;
    unsigned short* sbf = Bl + (size_t)N * D;  // N*N bf16 (134 MB) if ws permits

    size_t need = 4 * (size_t)N * D * sizeof(unsigned short) + (size_t)N * N * sizeof(unsigned short);
    bool bf16s = (ws_size >= need);

    split_kernel<<<(N * D / 4) / 256, 256, 0, stream>>>(z, Bh, Bl);
    zw_kernel<<<N / 32, 256, 0, stream>>>(z, W, Ah, Al);
    if (bf16s) {
        gemm_s_kernel<true><<<4096, 256, 0, stream>>>(Ah, Al, Bh, Bl, beta, sbf, nullptr);
        rownorm_kernel<true><<<N, 512, 0, stream>>>(out, Q, sbf);
    } else {
        gemm_s_kernel<false><<<4096, 256, 0, stream>>>(Ah, Al, Bh, Bl, beta, nullptr, out);
        rownorm_kernel<false><<<N, 512, 0, stream>>>(out, Q, nullptr);
    }
}